// Round 1
// baseline (264.598 us; speedup 1.0000x reference)
//
#include <hip/hip_runtime.h>
#include <hip/hip_bf16.h>
#include <stdint.h>

#define S_LEN 4096
#define HID   1024
#define NH    16
#define HD    64
#define HWIN  128

typedef __bf16 bf16x8 __attribute__((ext_vector_type(8)));
typedef float  f32x4  __attribute__((ext_vector_type(4)));

typedef const __attribute__((address_space(1))) unsigned int* gas_ptr;
typedef __attribute__((address_space(3))) unsigned int* las_ptr;

__device__ __forceinline__ float bf2f(unsigned short u) {
  union { float f; uint32_t i; } w; w.i = ((uint32_t)u) << 16; return w.f;
}
__device__ __forceinline__ unsigned short f2bf(float f) {
  union { float f; uint32_t i; } w; w.f = f;
  uint32_t r = (w.i + 0x7FFFu + ((w.i >> 16) & 1u)) >> 16;
  return (unsigned short)r;
}

__device__ __forceinline__ void gld_lds16(const void* g, void* l) {
  __builtin_amdgcn_global_load_lds((gas_ptr)g, (las_ptr)l, 16, 0, 0);
}

// ---------------------------------------------------------------- convert
__global__ __launch_bounds__(256) void convert_all(
    const float* __restrict__ x,
    const float* __restrict__ wq, const float* __restrict__ wk,
    const float* __restrict__ wv, const float* __restrict__ wo,
    unsigned short* __restrict__ xb,
    unsigned short* __restrict__ wqb, unsigned short* __restrict__ wkb,
    unsigned short* __restrict__ wvb, unsigned short* __restrict__ wob) {
  const float* in; unsigned short* out; int n4;
  switch (blockIdx.y) {
    case 0:  in = x;  out = xb;  n4 = (S_LEN * HID) / 4; break;
    case 1:  in = wq; out = wqb; n4 = (HID * HID) / 4;   break;
    case 2:  in = wk; out = wkb; n4 = (HID * HID) / 4;   break;
    case 3:  in = wv; out = wvb; n4 = (HID * HID) / 4;   break;
    default: in = wo; out = wob; n4 = (HID * HID) / 4;   break;
  }
  int i = blockIdx.x * 256 + threadIdx.x;
  if (i >= n4) return;
  float4 v = reinterpret_cast<const float4*>(in)[i];
  ushort4 o;
  o.x = f2bf(v.x); o.y = f2bf(v.y); o.z = f2bf(v.z); o.w = f2bf(v.w);
  reinterpret_cast<ushort4*>(out)[i] = o;
}

// ---------------------------------------------------------------- GEMM
// C[M,N] = A[M,K] * B[N,K]^T, M=4096, N=K=1024. bf16 in, fp32 accum.
// mode 0: bf16 C[r*HID+c]; mode 1: bf16 transposed C[c*S_LEN+r]; mode 2: f32 C[r*HID+c]
__device__ __forceinline__ void gemm_body(const unsigned short* __restrict__ A,
                                          const unsigned short* __restrict__ B,
                                          unsigned short* __restrict__ Cb,
                                          float* __restrict__ Cf, int mode) {
  __shared__ __align__(16) unsigned short As[128 * 32];
  __shared__ __align__(16) unsigned short Bs[128 * 32];
  constexpr int K = HID;
  const int tid  = threadIdx.x;
  const int lane = tid & 63;
  const int wave = tid >> 6;
  const int wm = wave >> 1, wn = wave & 1;
  const int m0 = blockIdx.x * 128;
  const int n0 = blockIdx.y * 128;

  f32x4 acc[4][4];
#pragma unroll
  for (int i = 0; i < 4; i++)
#pragma unroll
    for (int j = 0; j < 4; j++) acc[i][j] = f32x4{0.f, 0.f, 0.f, 0.f};

  const int c0 = tid, c1 = tid + 256;
  const unsigned short* A0 = A + (size_t)(m0 + (c0 >> 2)) * K + (c0 & 3) * 8;
  const unsigned short* A1 = A + (size_t)(m0 + (c1 >> 2)) * K + (c1 & 3) * 8;
  const unsigned short* B0 = B + (size_t)(n0 + (c0 >> 2)) * K + (c0 & 3) * 8;
  const unsigned short* B1 = B + (size_t)(n0 + (c1 >> 2)) * K + (c1 & 3) * 8;

  for (int k0 = 0; k0 < K; k0 += 32) {
    gld_lds16(A0 + k0, &As[c0 * 8]);
    gld_lds16(A1 + k0, &As[c1 * 8]);
    gld_lds16(B0 + k0, &Bs[c0 * 8]);
    gld_lds16(B1 + k0, &Bs[c1 * 8]);
    __syncthreads();
    bf16x8 a[4], b[4];
#pragma unroll
    for (int mi = 0; mi < 4; mi++)
      a[mi] = *reinterpret_cast<const bf16x8*>(
          &As[(wm * 64 + mi * 16 + (lane & 15)) * 32 + (lane >> 4) * 8]);
#pragma unroll
    for (int ni = 0; ni < 4; ni++)
      b[ni] = *reinterpret_cast<const bf16x8*>(
          &Bs[(wn * 64 + ni * 16 + (lane & 15)) * 32 + (lane >> 4) * 8]);
#pragma unroll
    for (int mi = 0; mi < 4; mi++)
#pragma unroll
      for (int ni = 0; ni < 4; ni++)
        acc[mi][ni] = __builtin_amdgcn_mfma_f32_16x16x32_bf16(a[mi], b[ni], acc[mi][ni], 0, 0, 0);
    __syncthreads();
  }

  const int rl = (lane >> 4) * 4;
  const int cl = lane & 15;
#pragma unroll
  for (int mi = 0; mi < 4; mi++)
#pragma unroll
    for (int ni = 0; ni < 4; ni++)
#pragma unroll
      for (int i = 0; i < 4; i++) {
        int r = m0 + wm * 64 + mi * 16 + rl + i;
        int c = n0 + wn * 64 + ni * 16 + cl;
        float v = acc[mi][ni][i];
        if (mode == 2)      Cf[(size_t)r * HID + c] = v;
        else if (mode == 1) Cb[(size_t)c * S_LEN + r] = f2bf(v);
        else                Cb[(size_t)r * HID + c] = f2bf(v);
      }
}

__global__ __launch_bounds__(256, 2) void gemm_qkv(
    const unsigned short* __restrict__ xb,
    const unsigned short* __restrict__ wqb, const unsigned short* __restrict__ wkb,
    const unsigned short* __restrict__ wvb,
    unsigned short* __restrict__ Qb, unsigned short* __restrict__ Kb,
    unsigned short* __restrict__ Vt) {
  const unsigned short* B = (blockIdx.z == 0) ? wqb : (blockIdx.z == 1) ? wkb : wvb;
  unsigned short* C       = (blockIdx.z == 0) ? Qb  : (blockIdx.z == 1) ? Kb  : Vt;
  int mode = (blockIdx.z == 2) ? 1 : 0;
  gemm_body(xb, B, C, nullptr, mode);
}

__global__ __launch_bounds__(256, 2) void gemm_proj(
    const unsigned short* __restrict__ Ob, const unsigned short* __restrict__ wob,
    float* __restrict__ out) {
  gemm_body(Ob, wob, nullptr, out, 2);
}

// ---------------------------------------------------------------- windowed attention
__global__ __launch_bounds__(256) void attn_win(const unsigned short* __restrict__ Qb,
                                                const unsigned short* __restrict__ Kb,
                                                const unsigned short* __restrict__ Vt,
                                                unsigned short* __restrict__ Ob) {
  __shared__ __align__(16) unsigned short Ps[4][16 * 32];
  const int h    = blockIdx.y;
  const int q0   = blockIdx.x * 64;
  const int lane = threadIdx.x & 63;
  const int wave = threadIdx.x >> 6;
  const int qr   = q0 + wave * 16;
  const int rl = (lane >> 4) * 4, cl = lane & 15;
  const float LOG2E = 1.44269504f;

  bf16x8 qf[2];
  {
    const unsigned short* qb = Qb + (size_t)(qr + cl) * HID + h * HD + (lane >> 4) * 8;
    qf[0] = *reinterpret_cast<const bf16x8*>(qb);
    qf[1] = *reinterpret_cast<const bf16x8*>(qb + 32);
  }
  float m_i[4] = {-1e30f, -1e30f, -1e30f, -1e30f};
  float l_i[4] = {0.f, 0.f, 0.f, 0.f};
  f32x4 oacc[4];
#pragma unroll
  for (int nt = 0; nt < 4; nt++) oacc[nt] = f32x4{0.f, 0.f, 0.f, 0.f};

  auto process = [&](int kb) {
    bf16x8 kf0[2], kf1[2];
    {
      const unsigned short* kb0 = Kb + (size_t)(kb + cl) * HID + h * HD + (lane >> 4) * 8;
      const unsigned short* kb1 = kb0 + 16 * HID;
      kf0[0] = *reinterpret_cast<const bf16x8*>(kb0);
      kf0[1] = *reinterpret_cast<const bf16x8*>(kb0 + 32);
      kf1[0] = *reinterpret_cast<const bf16x8*>(kb1);
      kf1[1] = *reinterpret_cast<const bf16x8*>(kb1 + 32);
    }
    f32x4 s[2];
    s[0] = f32x4{0.f, 0.f, 0.f, 0.f};
    s[1] = f32x4{0.f, 0.f, 0.f, 0.f};
    s[0] = __builtin_amdgcn_mfma_f32_16x16x32_bf16(qf[0], kf0[0], s[0], 0, 0, 0);
    s[0] = __builtin_amdgcn_mfma_f32_16x16x32_bf16(qf[1], kf0[1], s[0], 0, 0, 0);
    s[1] = __builtin_amdgcn_mfma_f32_16x16x32_bf16(qf[0], kf1[0], s[1], 0, 0, 0);
    s[1] = __builtin_amdgcn_mfma_f32_16x16x32_bf16(qf[1], kf1[1], s[1], 0, 0, 0);

    float sv[2][4];
    float tmax[4] = {-1e30f, -1e30f, -1e30f, -1e30f};
#pragma unroll
    for (int t = 0; t < 2; t++) {
      int col = kb + t * 16 + cl;
#pragma unroll
      for (int i = 0; i < 4; i++) {
        int row = qr + rl + i;
        int d = row - col;
        bool valid = (col == 0) || (d <= HWIN && d >= -HWIN);
        float v = valid ? s[t][i] * 0.125f : -1e30f;
        sv[t][i] = v;
        tmax[i] = fmaxf(tmax[i], v);
      }
    }
#pragma unroll
    for (int dd = 1; dd < 16; dd <<= 1)
#pragma unroll
      for (int i = 0; i < 4; i++) tmax[i] = fmaxf(tmax[i], __shfl_xor(tmax[i], dd, 16));

    float p[2][4], ps[4];
#pragma unroll
    for (int i = 0; i < 4; i++) {
      float mnew = fmaxf(m_i[i], tmax[i]);
      float fac  = exp2f((m_i[i] - mnew) * LOG2E);
      m_i[i] = mnew;
      p[0][i] = exp2f((sv[0][i] - mnew) * LOG2E);
      p[1][i] = exp2f((sv[1][i] - mnew) * LOG2E);
      ps[i] = p[0][i] + p[1][i];
      l_i[i] *= fac;
#pragma unroll
      for (int nt = 0; nt < 4; nt++) oacc[nt][i] *= fac;
    }
#pragma unroll
    for (int dd = 1; dd < 16; dd <<= 1)
#pragma unroll
      for (int i = 0; i < 4; i++) ps[i] += __shfl_xor(ps[i], dd, 16);
#pragma unroll
    for (int i = 0; i < 4; i++) l_i[i] += ps[i];

    // transpose P into A-fragment layout via per-wave LDS (same-wave DS is in-order)
#pragma unroll
    for (int t = 0; t < 2; t++)
#pragma unroll
      for (int i = 0; i < 4; i++)
        Ps[wave][(rl + i) * 32 + t * 16 + cl] = f2bf(p[t][i]);
    bf16x8 pf = *reinterpret_cast<const bf16x8*>(&Ps[wave][cl * 32 + (lane >> 4) * 8]);

#pragma unroll
    for (int nt = 0; nt < 4; nt++) {
      const unsigned short* vb =
          Vt + (size_t)(h * HD + nt * 16 + cl) * S_LEN + kb + (lane >> 4) * 8;
      bf16x8 vf = *reinterpret_cast<const bf16x8*>(vb);
      oacc[nt] = __builtin_amdgcn_mfma_f32_16x16x32_bf16(pf, vf, oacc[nt], 0, 0, 0);
    }
  };

  int kstart = q0 - HWIN; if (kstart < 0) kstart = 0;
  int kend = q0 + 64 + HWIN; if (kend > S_LEN) kend = S_LEN;
  if (kstart > 0) process(0);  // global key 0 (mask keeps only col 0)
  for (int kb = kstart; kb < kend; kb += 32) process(kb);

#pragma unroll
  for (int nt = 0; nt < 4; nt++)
#pragma unroll
    for (int i = 0; i < 4; i++) {
      float v = oacc[nt][i] / l_i[i];
      Ob[(size_t)(qr + rl + i) * HID + h * HD + nt * 16 + cl] = f2bf(v);
    }
}

// ---------------------------------------------------------------- global row 0
__global__ __launch_bounds__(256) void attn_row0(const unsigned short* __restrict__ Qb,
                                                 const unsigned short* __restrict__ Kb,
                                                 const unsigned short* __restrict__ Vt,
                                                 unsigned short* __restrict__ Ob) {
  const int h = blockIdx.x;
  const int tid = threadIdx.x;
  const int lane = tid & 63, wave = tid >> 6;
  __shared__ float sc[S_LEN];
  __shared__ float qsh[HD];
  __shared__ float red[8];
  __shared__ float red2[4][HD];
  const float LOG2E = 1.44269504f;

  if (tid < HD) qsh[tid] = bf2f(Qb[h * HD + tid]);
  __syncthreads();
  for (int k = tid; k < S_LEN; k += 256) {
    const unsigned short* kr = Kb + (size_t)k * HID + h * HD;
    float acc = 0.f;
#pragma unroll
    for (int d = 0; d < HD; d++) acc += qsh[d] * bf2f(kr[d]);
    sc[k] = acc * 0.125f;
  }
  __syncthreads();
  float lm = -1e30f;
  for (int k = tid; k < S_LEN; k += 256) lm = fmaxf(lm, sc[k]);
#pragma unroll
  for (int d = 1; d < 64; d <<= 1) lm = fmaxf(lm, __shfl_xor(lm, d, 64));
  if (lane == 0) red[wave] = lm;
  __syncthreads();
  float gm = fmaxf(fmaxf(red[0], red[1]), fmaxf(red[2], red[3]));
  float lsum = 0.f;
  for (int k = tid; k < S_LEN; k += 256) {
    float p = exp2f((sc[k] - gm) * LOG2E);
    sc[k] = p;
    lsum += p;
  }
#pragma unroll
  for (int d = 1; d < 64; d <<= 1) lsum += __shfl_xor(lsum, d, 64);
  if (lane == 0) red[4 + wave] = lsum;
  __syncthreads();
  float gs = red[4] + red[5] + red[6] + red[7];
  const int dd = tid & 63, grp = tid >> 6;
  const unsigned short* vrow = Vt + (size_t)(h * HD + dd) * S_LEN;
  float acc = 0.f;
  for (int k = grp; k < S_LEN; k += 4) acc += sc[k] * bf2f(vrow[k]);
  red2[grp][dd] = acc;
  __syncthreads();
  if (tid < HD) {
    float v = (red2[0][tid] + red2[1][tid] + red2[2][tid] + red2[3][tid]) / gs;
    Ob[h * HD + tid] = f2bf(v);
  }
}

// ---------------------------------------------------------------- launch
extern "C" void kernel_launch(void* const* d_in, const int* in_sizes, int n_in,
                              void* d_out, int out_size, void* d_ws, size_t ws_size,
                              hipStream_t stream) {
  const float* x  = (const float*)d_in[0];
  const float* wq = (const float*)d_in[1];
  const float* wk = (const float*)d_in[2];
  const float* wv = (const float*)d_in[3];
  const float* wo = (const float*)d_in[4];
  float* out = (float*)d_out;
  char* ws = (char*)d_ws;
  const size_t MB = 1024ull * 1024ull;
  unsigned short* xb  = (unsigned short*)(ws + 0 * MB);
  unsigned short* wqb = (unsigned short*)(ws + 8 * MB);
  unsigned short* wkb = (unsigned short*)(ws + 10 * MB);
  unsigned short* wvb = (unsigned short*)(ws + 12 * MB);
  unsigned short* wob = (unsigned short*)(ws + 14 * MB);
  unsigned short* Qb  = (unsigned short*)(ws + 16 * MB);
  unsigned short* Kb  = (unsigned short*)(ws + 24 * MB);
  unsigned short* Vt  = (unsigned short*)(ws + 32 * MB);
  unsigned short* Ob  = (unsigned short*)(ws + 40 * MB);

  dim3 blk(256);
  convert_all<<<dim3((S_LEN * HID / 4 + 255) / 256, 5), blk, 0, stream>>>(
      x, wq, wk, wv, wo, xb, wqb, wkb, wvb, wob);
  gemm_qkv<<<dim3(S_LEN / 128, HID / 128, 3), blk, 0, stream>>>(
      xb, wqb, wkb, wvb, Qb, Kb, Vt);
  attn_win<<<dim3(S_LEN / 64, NH), blk, 0, stream>>>(Qb, Kb, Vt, Ob);
  attn_row0<<<dim3(NH), blk, 0, stream>>>(Qb, Kb, Vt, Ob);
  gemm_proj<<<dim3(S_LEN / 128, HID / 128), blk, 0, stream>>>(Ob, wob, out);
}

// Round 2
// 126.294 us; speedup vs baseline: 2.0951x; 2.0951x over previous
//
#include <hip/hip_runtime.h>
#include <hip/hip_bf16.h>
#include <stdint.h>

#define S_LEN 4096
#define HID   1024
#define NH    16
#define HD    64
#define HWIN  128

typedef __bf16 bf16x8 __attribute__((ext_vector_type(8)));
typedef float  f32x4  __attribute__((ext_vector_type(4)));
typedef unsigned short u16x8 __attribute__((ext_vector_type(8)));

typedef const __attribute__((address_space(1))) unsigned int* gas_ptr;
typedef __attribute__((address_space(3))) unsigned int* las_ptr;

__device__ __forceinline__ float bf2f(unsigned short u) {
  union { float f; uint32_t i; } w; w.i = ((uint32_t)u) << 16; return w.f;
}
__device__ __forceinline__ unsigned short f2bf(float f) {
  union { float f; uint32_t i; } w; w.f = f;
  uint32_t r = (w.i + 0x7FFFu + ((w.i >> 16) & 1u)) >> 16;
  return (unsigned short)r;
}

__device__ __forceinline__ void gld_lds16(const void* g, void* l) {
  __builtin_amdgcn_global_load_lds((gas_ptr)g, (las_ptr)l, 16, 0, 0);
}

// ---------------------------------------------------------------- convert
__global__ __launch_bounds__(256) void convert_all(
    const float* __restrict__ x,
    const float* __restrict__ wq, const float* __restrict__ wk,
    const float* __restrict__ wv, const float* __restrict__ wo,
    unsigned short* __restrict__ xb,
    unsigned short* __restrict__ wqb, unsigned short* __restrict__ wkb,
    unsigned short* __restrict__ wvb, unsigned short* __restrict__ wob) {
  const float* in; unsigned short* out; int n4;
  switch (blockIdx.y) {
    case 0:  in = x;  out = xb;  n4 = (S_LEN * HID) / 4; break;
    case 1:  in = wq; out = wqb; n4 = (HID * HID) / 4;   break;
    case 2:  in = wk; out = wkb; n4 = (HID * HID) / 4;   break;
    case 3:  in = wv; out = wvb; n4 = (HID * HID) / 4;   break;
    default: in = wo; out = wob; n4 = (HID * HID) / 4;   break;
  }
  int i = blockIdx.x * 256 + threadIdx.x;
  if (i >= n4) return;
  float4 v = reinterpret_cast<const float4*>(in)[i];
  ushort4 o;
  o.x = f2bf(v.x); o.y = f2bf(v.y); o.z = f2bf(v.z); o.w = f2bf(v.w);
  reinterpret_cast<ushort4*>(out)[i] = o;
}

// ---------------------------------------------------------------- GEMM
// C[M,N] = A[M,K] * B[N,K]^T, M=4096, N=K=1024. bf16 in, fp32 accum.
// mode 0: bf16 C[r*HID+c]; mode 1: bf16 transposed C[c*S_LEN+r]; mode 2: f32 C[r*HID+c]
__device__ __forceinline__ void gemm_body(const unsigned short* __restrict__ A,
                                          const unsigned short* __restrict__ B,
                                          unsigned short* __restrict__ Cb,
                                          float* __restrict__ Cf, int mode) {
  __shared__ __align__(16) unsigned short As[128 * 32];
  __shared__ __align__(16) unsigned short Bs[128 * 32];
  constexpr int K = HID;
  const int tid  = threadIdx.x;
  const int lane = tid & 63;
  const int wave = tid >> 6;
  const int wm = wave >> 1, wn = wave & 1;
  const int m0 = blockIdx.x * 128;
  const int n0 = blockIdx.y * 128;

  f32x4 acc[4][4];
#pragma unroll
  for (int i = 0; i < 4; i++)
#pragma unroll
    for (int j = 0; j < 4; j++) acc[i][j] = f32x4{0.f, 0.f, 0.f, 0.f};

  const int c0 = tid, c1 = tid + 256;
  const unsigned short* A0 = A + (size_t)(m0 + (c0 >> 2)) * K + (c0 & 3) * 8;
  const unsigned short* A1 = A + (size_t)(m0 + (c1 >> 2)) * K + (c1 & 3) * 8;
  const unsigned short* B0 = B + (size_t)(n0 + (c0 >> 2)) * K + (c0 & 3) * 8;
  const unsigned short* B1 = B + (size_t)(n0 + (c1 >> 2)) * K + (c1 & 3) * 8;

  for (int k0 = 0; k0 < K; k0 += 32) {
    gld_lds16(A0 + k0, &As[c0 * 8]);
    gld_lds16(A1 + k0, &As[c1 * 8]);
    gld_lds16(B0 + k0, &Bs[c0 * 8]);
    gld_lds16(B1 + k0, &Bs[c1 * 8]);
    __syncthreads();
    bf16x8 a[4], b[4];
#pragma unroll
    for (int mi = 0; mi < 4; mi++)
      a[mi] = *reinterpret_cast<const bf16x8*>(
          &As[(wm * 64 + mi * 16 + (lane & 15)) * 32 + (lane >> 4) * 8]);
#pragma unroll
    for (int ni = 0; ni < 4; ni++)
      b[ni] = *reinterpret_cast<const bf16x8*>(
          &Bs[(wn * 64 + ni * 16 + (lane & 15)) * 32 + (lane >> 4) * 8]);
#pragma unroll
    for (int mi = 0; mi < 4; mi++)
#pragma unroll
      for (int ni = 0; ni < 4; ni++)
        acc[mi][ni] = __builtin_amdgcn_mfma_f32_16x16x32_bf16(a[mi], b[ni], acc[mi][ni], 0, 0, 0);
    __syncthreads();
  }

  const int rl = (lane >> 4) * 4;
  const int cl = lane & 15;
#pragma unroll
  for (int mi = 0; mi < 4; mi++)
#pragma unroll
    for (int ni = 0; ni < 4; ni++)
#pragma unroll
      for (int i = 0; i < 4; i++) {
        int r = m0 + wm * 64 + mi * 16 + rl + i;
        int c = n0 + wn * 64 + ni * 16 + cl;
        float v = acc[mi][ni][i];
        if (mode == 2)      Cf[(size_t)r * HID + c] = v;
        else if (mode == 1) Cb[(size_t)c * S_LEN + r] = f2bf(v);
        else                Cb[(size_t)r * HID + c] = f2bf(v);
      }
}

__global__ __launch_bounds__(256, 2) void gemm_qkv(
    const unsigned short* __restrict__ xb,
    const unsigned short* __restrict__ wqb, const unsigned short* __restrict__ wkb,
    const unsigned short* __restrict__ wvb,
    unsigned short* __restrict__ Qb, unsigned short* __restrict__ Kb,
    unsigned short* __restrict__ Vt) {
  const unsigned short* B = (blockIdx.z == 0) ? wqb : (blockIdx.z == 1) ? wkb : wvb;
  unsigned short* C       = (blockIdx.z == 0) ? Qb  : (blockIdx.z == 1) ? Kb  : Vt;
  int mode = (blockIdx.z == 2) ? 1 : 0;
  gemm_body(xb, B, C, nullptr, mode);
}

__global__ __launch_bounds__(256, 2) void gemm_proj(
    const unsigned short* __restrict__ Ob, const unsigned short* __restrict__ wob,
    float* __restrict__ out) {
  gemm_body(Ob, wob, nullptr, out, 2);
}

// ---------------------------------------------------------------- windowed attention
__global__ __launch_bounds__(256) void attn_win(const unsigned short* __restrict__ Qb,
                                                const unsigned short* __restrict__ Kb,
                                                const unsigned short* __restrict__ Vt,
                                                unsigned short* __restrict__ Ob) {
  __shared__ __align__(16) unsigned short Ps[4][16 * 32];
  const int h    = blockIdx.y;
  const int q0   = blockIdx.x * 64;
  const int lane = threadIdx.x & 63;
  const int wave = threadIdx.x >> 6;
  const int qr   = q0 + wave * 16;
  const int rl = (lane >> 4) * 4, cl = lane & 15;
  const float LOG2E = 1.44269504f;

  bf16x8 qf[2];
  {
    const unsigned short* qb = Qb + (size_t)(qr + cl) * HID + h * HD + (lane >> 4) * 8;
    qf[0] = *reinterpret_cast<const bf16x8*>(qb);
    qf[1] = *reinterpret_cast<const bf16x8*>(qb + 32);
  }
  float m_i[4] = {-1e30f, -1e30f, -1e30f, -1e30f};
  float l_i[4] = {0.f, 0.f, 0.f, 0.f};
  f32x4 oacc[4];
#pragma unroll
  for (int nt = 0; nt < 4; nt++) oacc[nt] = f32x4{0.f, 0.f, 0.f, 0.f};

  auto process = [&](int kb) {
    bf16x8 kf0[2], kf1[2];
    {
      const unsigned short* kb0 = Kb + (size_t)(kb + cl) * HID + h * HD + (lane >> 4) * 8;
      const unsigned short* kb1 = kb0 + 16 * HID;
      kf0[0] = *reinterpret_cast<const bf16x8*>(kb0);
      kf0[1] = *reinterpret_cast<const bf16x8*>(kb0 + 32);
      kf1[0] = *reinterpret_cast<const bf16x8*>(kb1);
      kf1[1] = *reinterpret_cast<const bf16x8*>(kb1 + 32);
    }
    f32x4 s[2];
    s[0] = f32x4{0.f, 0.f, 0.f, 0.f};
    s[1] = f32x4{0.f, 0.f, 0.f, 0.f};
    s[0] = __builtin_amdgcn_mfma_f32_16x16x32_bf16(qf[0], kf0[0], s[0], 0, 0, 0);
    s[0] = __builtin_amdgcn_mfma_f32_16x16x32_bf16(qf[1], kf0[1], s[0], 0, 0, 0);
    s[1] = __builtin_amdgcn_mfma_f32_16x16x32_bf16(qf[0], kf1[0], s[1], 0, 0, 0);
    s[1] = __builtin_amdgcn_mfma_f32_16x16x32_bf16(qf[1], kf1[1], s[1], 0, 0, 0);

    float sv[2][4];
    float tmax[4] = {-1e30f, -1e30f, -1e30f, -1e30f};
#pragma unroll
    for (int t = 0; t < 2; t++) {
      int col = kb + t * 16 + cl;
#pragma unroll
      for (int i = 0; i < 4; i++) {
        int row = qr + rl + i;
        int d = row - col;
        bool valid = (col == 0) || (d <= HWIN && d >= -HWIN);
        float v = valid ? s[t][i] * 0.125f : -1e30f;
        sv[t][i] = v;
        tmax[i] = fmaxf(tmax[i], v);
      }
    }
#pragma unroll
    for (int dd = 1; dd < 16; dd <<= 1)
#pragma unroll
      for (int i = 0; i < 4; i++) tmax[i] = fmaxf(tmax[i], __shfl_xor(tmax[i], dd, 16));

    float p[2][4], ps[4];
#pragma unroll
    for (int i = 0; i < 4; i++) {
      float mnew = fmaxf(m_i[i], tmax[i]);
      float fac  = exp2f((m_i[i] - mnew) * LOG2E);
      m_i[i] = mnew;
      p[0][i] = exp2f((sv[0][i] - mnew) * LOG2E);
      p[1][i] = exp2f((sv[1][i] - mnew) * LOG2E);
      ps[i] = p[0][i] + p[1][i];
      l_i[i] *= fac;
#pragma unroll
      for (int nt = 0; nt < 4; nt++) oacc[nt][i] *= fac;
    }
#pragma unroll
    for (int dd = 1; dd < 16; dd <<= 1)
#pragma unroll
      for (int i = 0; i < 4; i++) ps[i] += __shfl_xor(ps[i], dd, 16);
#pragma unroll
    for (int i = 0; i < 4; i++) l_i[i] += ps[i];

    // transpose P into A-fragment layout via per-wave LDS (same-wave DS is in-order)
#pragma unroll
    for (int t = 0; t < 2; t++)
#pragma unroll
      for (int i = 0; i < 4; i++)
        Ps[wave][(rl + i) * 32 + t * 16 + cl] = f2bf(p[t][i]);
    bf16x8 pf = *reinterpret_cast<const bf16x8*>(&Ps[wave][cl * 32 + (lane >> 4) * 8]);

#pragma unroll
    for (int nt = 0; nt < 4; nt++) {
      const unsigned short* vb =
          Vt + (size_t)(h * HD + nt * 16 + cl) * S_LEN + kb + (lane >> 4) * 8;
      bf16x8 vf = *reinterpret_cast<const bf16x8*>(vb);
      oacc[nt] = __builtin_amdgcn_mfma_f32_16x16x32_bf16(pf, vf, oacc[nt], 0, 0, 0);
    }
  };

  int kstart = q0 - HWIN; if (kstart < 0) kstart = 0;
  int kend = q0 + 64 + HWIN; if (kend > S_LEN) kend = S_LEN;
  if (kstart > 0) process(0);  // global key 0 (mask keeps only col 0)
  for (int kb = kstart; kb < kend; kb += 32) process(kb);

#pragma unroll
  for (int nt = 0; nt < 4; nt++)
#pragma unroll
    for (int i = 0; i < 4; i++) {
      float v = oacc[nt][i] / l_i[i];
      Ob[(size_t)(qr + rl + i) * HID + h * HD + nt * 16 + cl] = f2bf(v);
    }
}

// ---------------------------------------------------------------- global row 0 (parallel)
// Phase A: 16 chunks x 16 heads; each block does 256 keys for one head.
__global__ __launch_bounds__(256) void attn_row0_part(
    const unsigned short* __restrict__ Qb,
    const unsigned short* __restrict__ Kb,
    const unsigned short* __restrict__ Vt,
    float* __restrict__ mw, float* __restrict__ lw, float* __restrict__ ow) {
  const int h = blockIdx.y, c = blockIdx.x;
  const int tid = threadIdx.x, lane = tid & 63, wave = tid >> 6;
  const int k = c * 256 + tid;
  __shared__ float qsh[HD];
  __shared__ float ps[256];
  __shared__ float redm[4], redl[4];
  __shared__ float red2[4][HD];
  const float LOG2E = 1.44269504f;

  if (tid < HD) qsh[tid] = bf2f(Qb[h * HD + tid]);
  __syncthreads();

  // QK: one key per thread, vectorized 128B row read
  const unsigned short* kr = Kb + (size_t)k * HID + h * HD;
  float acc = 0.f;
#pragma unroll
  for (int v8 = 0; v8 < 8; v8++) {
    u16x8 kv = *reinterpret_cast<const u16x8*>(kr + v8 * 8);
#pragma unroll
    for (int j = 0; j < 8; j++) acc += qsh[v8 * 8 + j] * bf2f(kv[j]);
  }
  float s = acc * 0.125f;

  // chunk max
  float m = s;
#pragma unroll
  for (int d = 1; d < 64; d <<= 1) m = fmaxf(m, __shfl_xor(m, d, 64));
  if (lane == 0) redm[wave] = m;
  __syncthreads();
  float m_c = fmaxf(fmaxf(redm[0], redm[1]), fmaxf(redm[2], redm[3]));

  float p = exp2f((s - m_c) * LOG2E);
  ps[tid] = p;
  float l = p;
#pragma unroll
  for (int d = 1; d < 64; d <<= 1) l += __shfl_xor(l, d, 64);
  if (lane == 0) redl[wave] = l;
  __syncthreads();
  float l_c = redl[0] + redl[1] + redl[2] + redl[3];

  // PV partial: thread t handles dim d=t&63, key-subrange g=t>>6
  const int d = tid & 63, g = tid >> 6;
  const unsigned short* vrow = Vt + (size_t)(h * HD + d) * S_LEN + c * 256 + g * 64;
  float a2 = 0.f;
#pragma unroll
  for (int v8 = 0; v8 < 8; v8++) {
    u16x8 vv = *reinterpret_cast<const u16x8*>(vrow + v8 * 8);
#pragma unroll
    for (int j = 0; j < 8; j++) a2 += ps[g * 64 + v8 * 8 + j] * bf2f(vv[j]);
  }
  red2[g][d] = a2;
  __syncthreads();
  if (tid < HD) {
    float o = red2[0][tid] + red2[1][tid] + red2[2][tid] + red2[3][tid];
    ow[(size_t)(h * 16 + c) * HD + tid] = o;
  }
  if (tid == 0) { mw[h * 16 + c] = m_c; lw[h * 16 + c] = l_c; }
}

// Phase B: combine 16 chunk partials per head, overwrite Ob row 0.
__global__ __launch_bounds__(64) void attn_row0_fin(
    const float* __restrict__ mw, const float* __restrict__ lw,
    const float* __restrict__ ow, unsigned short* __restrict__ Ob) {
  const int h = blockIdx.x, d = threadIdx.x;
  const float LOG2E = 1.44269504f;
  float m_g = -1e30f;
#pragma unroll
  for (int c = 0; c < 16; c++) m_g = fmaxf(m_g, mw[h * 16 + c]);
  float lsum = 0.f, osum = 0.f;
#pragma unroll
  for (int c = 0; c < 16; c++) {
    float w = exp2f((mw[h * 16 + c] - m_g) * LOG2E);
    lsum += lw[h * 16 + c] * w;
    osum += ow[(size_t)(h * 16 + c) * HD + d] * w;
  }
  Ob[h * HD + d] = f2bf(osum / lsum);
}

// ---------------------------------------------------------------- launch
extern "C" void kernel_launch(void* const* d_in, const int* in_sizes, int n_in,
                              void* d_out, int out_size, void* d_ws, size_t ws_size,
                              hipStream_t stream) {
  const float* x  = (const float*)d_in[0];
  const float* wq = (const float*)d_in[1];
  const float* wk = (const float*)d_in[2];
  const float* wv = (const float*)d_in[3];
  const float* wo = (const float*)d_in[4];
  float* out = (float*)d_out;
  char* ws = (char*)d_ws;
  const size_t MB = 1024ull * 1024ull;
  unsigned short* xb  = (unsigned short*)(ws + 0 * MB);
  unsigned short* wqb = (unsigned short*)(ws + 8 * MB);
  unsigned short* wkb = (unsigned short*)(ws + 10 * MB);
  unsigned short* wvb = (unsigned short*)(ws + 12 * MB);
  unsigned short* wob = (unsigned short*)(ws + 14 * MB);
  unsigned short* Qb  = (unsigned short*)(ws + 16 * MB);
  unsigned short* Kb  = (unsigned short*)(ws + 24 * MB);
  unsigned short* Vt  = (unsigned short*)(ws + 32 * MB);
  unsigned short* Ob  = (unsigned short*)(ws + 40 * MB);
  float* mw = (float*)(ws + 48 * MB);
  float* lw = (float*)(ws + 48 * MB + 4096);
  float* ow = (float*)(ws + 48 * MB + 8192);

  dim3 blk(256);
  convert_all<<<dim3((S_LEN * HID / 4 + 255) / 256, 5), blk, 0, stream>>>(
      x, wq, wk, wv, wo, xb, wqb, wkb, wvb, wob);
  gemm_qkv<<<dim3(S_LEN / 128, HID / 128, 3), blk, 0, stream>>>(
      xb, wqb, wkb, wvb, Qb, Kb, Vt);
  attn_win<<<dim3(S_LEN / 64, NH), blk, 0, stream>>>(Qb, Kb, Vt, Ob);
  attn_row0_part<<<dim3(16, NH), blk, 0, stream>>>(Qb, Kb, Vt, mw, lw, ow);
  attn_row0_fin<<<dim3(NH), dim3(64), 0, stream>>>(mw, lw, ow, Ob);
  gemm_proj<<<dim3(S_LEN / 128, HID / 128), blk, 0, stream>>>(Ob, wob, out);
}